// Round 11
// baseline (39.117 us; speedup 1.0000x reference)
//
#include <hip/hip_runtime.h>
#include <hip/hip_bf16.h>

// Problem constants: B=32768, D=768, C=200.
#define NROWS 32768
#define DIMS  768
#define NC    200
#define CPAD  256
#define KSTEP 32
#define NSTEP (DIMS / KSTEP)   // 24
#define ROWSB 64               // M-tile rows per block -> grid 512

typedef __attribute__((ext_vector_type(8))) short short8;   // 8 bf16
typedef __attribute__((ext_vector_type(4))) float f32x4;

#define SFENCE    asm volatile("" ::: "memory")
#define WAITV2    asm volatile("s_waitcnt vmcnt(2)" ::: "memory")
#define WAITV6    asm volatile("s_waitcnt vmcnt(6)" ::: "memory")
#define WAITV2L0  asm volatile("s_waitcnt vmcnt(2) lgkmcnt(0)" ::: "memory")

__device__ __forceinline__ unsigned pk_bf16(float lo, float hi) {
  union { __hip_bfloat162 h; unsigned u; } c;
  c.h = __float22bfloat162_rn(make_float2(lo, hi));
  return c.u;
}

// async global->LDS DMA, 16 B per lane, LDS dest = wave-uniform base + lane*16
__device__ __forceinline__ void glds16(const void* g, void* l) {
  __builtin_amdgcn_global_load_lds(
      (const __attribute__((address_space(1))) unsigned int*)g,
      (__attribute__((address_space(3))) unsigned int*)l, 16, 0, 0);
}

// Kernel 1 (verified round 10): L2-normalize centers -> bf16, K-blocked layout
// WITH the quad swizzle pre-baked: (c,d): ks=d>>5, q=(d&31)>>3, j=d&7 stored at
// ks*CPAD*32 + c*32 + (q ^ ((c>>1)&3))*8 + j. Rows >= NC zero. Zeroes out[0].
__global__ __launch_bounds__(256) void prep_centers_k(const float* __restrict__ centers,
                                                      short* __restrict__ cnb2,
                                                      float* __restrict__ out) {
  const int c = blockIdx.x;
  const int tid = threadIdx.x;
  if (c == 0 && tid == 0) out[0] = 0.f;
  const int cswz = (c >> 1) & 3;
  if (c >= NC) {
    for (int d = tid; d < DIMS; d += 256)
      cnb2[(d >> 5) * (CPAD * KSTEP) + c * KSTEP + d % 32] = 0;
    return;
  }
  float ssq = 0.f;
  for (int d = tid; d < DIMS; d += 256) {
    float v = centers[c * DIMS + d];
    ssq += v * v;
  }
#pragma unroll
  for (int off = 32; off > 0; off >>= 1) ssq += __shfl_down(ssq, off);
  __shared__ float red[4];
  const int wid = tid >> 6, lane = tid & 63;
  if (lane == 0) red[wid] = ssq;
  __syncthreads();
  const float tot = red[0] + red[1] + red[2] + red[3];
  const float inv = 1.f / fmaxf(sqrtf(tot), 1e-8f);
  for (int d = tid; d < DIMS; d += 256) {
    const float v = centers[c * DIMS + d] * inv;
    union { __hip_bfloat16 h; short s; } cv;
    cv.h = __float2bfloat16(v);
    const int ks = d >> 5, dk = d & 31, q = dk >> 3, j = dk & 7;
    cnb2[ks * (CPAD * KSTEP) + c * KSTEP + ((q ^ cswz) * 8 + j)] = cv.s;
  }
}

// Kernel 2: round-10 structure with COUNTED vmcnt + raw s_barrier (T3/T4).
// Phase s: DMAB(s+1->nxt) | LOADA(s+2) | COMPUTE(cur) | vmcnt(6) | WRITEA(s+1)
//          | vmcnt(2) lgkmcnt(0) | s_barrier.
// A HBM loads stay in flight across TWO barriers; B DMAs span the compute phase.
// Uniform 6 vmem issues per phase (tail clamped, ssq guarded) keep counts exact.
// MFMA frag mapping (verified rounds 2-10): A lane=A[m][kg*8+j];
// B lane=B[kg*8+j][m]; D: col=m, row=kg*4+reg.
__global__ __launch_bounds__(256) void cos_loss_k(
    const float* __restrict__ feats,
    const short* __restrict__ cnb2,
    const int* __restrict__ labels,
    const int* __restrict__ labelled,
    float* __restrict__ out) {
  const int tid = threadIdx.x;
  const int w = tid >> 6;            // wave id = column group (64 cols)
  const int lane = tid & 63;
  const int m = lane & 15;
  const int kg = lane >> 4;
  const int sq = (kg ^ ((m >> 1) & 3)) * 8;   // frag quad offset (A and B)
  const int rowBase = blockIdx.x * ROWSB;

  __shared__ short As[2][ROWSB][32];   // 8 KB
  __shared__ short Bs[2][CPAD][32];    // 32 KB
  __shared__ float invs[ROWSB];
  __shared__ int   labLds[ROWSB];
  __shared__ int   lblLds[ROWSB];
  __shared__ float l1part[4][ROWSB];
  __shared__ float alpart[4][ROWSB];

  if (tid < ROWSB) {
    labLds[tid] = labels[rowBase + tid];
    lblLds[tid] = labelled[rowBase + tid];
  }

  // A staging: 4 thr/row, thread covers 8 floats (one quad) of the 32-k slice
  const int arow = tid >> 2;            // 0..63
  const int aq   = tid & 3;
  const int aswz = (arow >> 1) & 3;
  const float* asrc = feats + (size_t)(rowBase + arow) * DIMS + aq * 8;
  short* adst[2] = { &As[0][arow][(aq ^ aswz) * 8], &As[1][arow][(aq ^ aswz) * 8] };
  // B DMA: wave w stages its own cols w*64..w*64+63 = 4 chunks of 1 KB
  const short* bbase = cnb2 + (size_t)(w * 64) * KSTEP + lane * 8;

  f32x4 acc[4][4];
#pragma unroll
  for (int mi = 0; mi < 4; ++mi)
#pragma unroll
    for (int ni = 0; ni < 4; ++ni) acc[mi][ni] = (f32x4){0.f, 0.f, 0.f, 0.f};

  float ssq = 0.f;
  float4 S0_lo, S0_hi, S1_lo, S1_hi;   // depth-2 A slots (static names)

#define LOADA(P, step) do {                                              \
    const float* ap_ = asrc + (step) * KSTEP;                            \
    P##_lo = *(const float4*)(ap_);                                      \
    P##_hi = *(const float4*)(ap_ + 4);                                  \
  } while (0)

#define WRITEA(P, buf, guard) do {                                       \
    if (guard) {                                                         \
      ssq += P##_lo.x*P##_lo.x + P##_lo.y*P##_lo.y                       \
           + P##_lo.z*P##_lo.z + P##_lo.w*P##_lo.w;                      \
      ssq += P##_hi.x*P##_hi.x + P##_hi.y*P##_hi.y                       \
           + P##_hi.z*P##_hi.z + P##_hi.w*P##_hi.w;                      \
    }                                                                    \
    union { short8 s; unsigned u[4]; } p_;                               \
    p_.u[0] = pk_bf16(P##_lo.x, P##_lo.y);                               \
    p_.u[1] = pk_bf16(P##_lo.z, P##_lo.w);                               \
    p_.u[2] = pk_bf16(P##_hi.x, P##_hi.y);                               \
    p_.u[3] = pk_bf16(P##_hi.z, P##_hi.w);                               \
    *(short8*)(adst[(buf)]) = p_.s;                                      \
  } while (0)

#define DMAB(step, buf) do {                                             \
    const short* g_ = bbase + (size_t)(step) * (CPAD * KSTEP);           \
    glds16(g_ + 0 * (16 * KSTEP), &Bs[(buf)][w * 64 + 0 * 16][0]);       \
    glds16(g_ + 1 * (16 * KSTEP), &Bs[(buf)][w * 64 + 1 * 16][0]);       \
    glds16(g_ + 2 * (16 * KSTEP), &Bs[(buf)][w * 64 + 2 * 16][0]);       \
    glds16(g_ + 3 * (16 * KSTEP), &Bs[(buf)][w * 64 + 3 * 16][0]);       \
  } while (0)

#define COMPUTE(buf) do {                                                \
    short8 af[4], bf[4];                                                 \
    _Pragma("unroll")                                                    \
    for (int mi = 0; mi < 4; ++mi)                                       \
      af[mi] = *(const short8*)(&As[(buf)][mi * 16 + m][sq]);            \
    _Pragma("unroll")                                                    \
    for (int ni = 0; ni < 4; ++ni)                                       \
      bf[ni] = *(const short8*)(&Bs[(buf)][w * 64 + ni * 16 + m][sq]);   \
    _Pragma("unroll")                                                    \
    for (int mi = 0; mi < 4; ++mi)                                       \
      _Pragma("unroll")                                                  \
      for (int ni = 0; ni < 4; ++ni)                                     \
        acc[mi][ni] = __builtin_amdgcn_mfma_f32_16x16x32_bf16(           \
            af[mi], bf[ni], acc[mi][ni], 0, 0, 0);                       \
  } while (0)

  // One phase: uniform 4+2 vmem issues; counted waits; raw barrier.
#define PHASE(s, CUR, NXT, SCONS, SLOAD) do {                            \
    const int sn_ = ((s) + 1 < NSTEP) ? (s) + 1 : NSTEP - 1;             \
    const int sl_ = ((s) + 2 < NSTEP) ? (s) + 2 : NSTEP - 1;             \
    DMAB(sn_, NXT);                                                      \
    SFENCE;                                                              \
    LOADA(SLOAD, sl_);                                                   \
    SFENCE;                                                              \
    COMPUTE(CUR);                                                        \
    WAITV6;                                                              \
    WRITEA(SCONS, NXT, (s) + 1 < NSTEP);                                 \
    WAITV2L0;                                                            \
    __builtin_amdgcn_s_barrier();                                        \
  } while (0)

  // prologue: stage step 0; leave LOADA(S1,1) in flight across the barrier
  DMAB(0, 0);
  SFENCE;
  LOADA(S0, 0);
  LOADA(S1, 1);
  SFENCE;
  WAITV2;                       // DMA(0) + S0 done; S1 still outstanding
  WRITEA(S0, 0, true);
  WAITV2L0;
  __builtin_amdgcn_s_barrier();

  for (int ks = 0; ks < NSTEP; ks += 2) {
    PHASE(ks,     0, 1, S1, S0);
    PHASE(ks + 1, 1, 0, S0, S1);
  }

#undef LOADA
#undef WRITEA
#undef DMAB
#undef COMPUTE
#undef PHASE

  // ---- row inverse norms (fp32): reduce over the 4 staging threads of a row ----
  ssq += __shfl_xor(ssq, 1);
  ssq += __shfl_xor(ssq, 2);
  if ((tid & 3) == 0) invs[arow] = 1.f / fmaxf(sqrtf(ssq), 1e-8f);
  __syncthreads();

  // ---- epilogue: per-row l1 and label-|cos| ----
#pragma unroll
  for (int mi = 0; mi < 4; ++mi) {
    float l1r[4] = {0.f, 0.f, 0.f, 0.f};
    float alr[4] = {0.f, 0.f, 0.f, 0.f};
    float iv[4];
    int labr[4];
#pragma unroll
    for (int r = 0; r < 4; ++r) {
      const int row = mi * 16 + kg * 4 + r;
      iv[r] = invs[row];
      labr[r] = labLds[row];
    }
#pragma unroll
    for (int ni = 0; ni < 4; ++ni) {
      const int col = w * 64 + ni * 16 + m;
#pragma unroll
      for (int r = 0; r < 4; ++r) {
        const float a = fabsf(acc[mi][ni][r] * iv[r]);
        l1r[r] += a;
        if (col == labr[r]) alr[r] += a;
      }
    }
#pragma unroll
    for (int r = 0; r < 4; ++r) {
#pragma unroll
      for (int off = 1; off < 16; off <<= 1) {
        l1r[r] += __shfl_xor(l1r[r], off);
        alr[r] += __shfl_xor(alr[r], off);
      }
    }
    if (m == 0) {
#pragma unroll
      for (int r = 0; r < 4; ++r) {
        l1part[w][mi * 16 + kg * 4 + r] = l1r[r];
        alpart[w][mi * 16 + kg * 4 + r] = alr[r];
      }
    }
  }
  __syncthreads();

  if (tid < ROWSB) {
    const float L = l1part[0][tid] + l1part[1][tid] + l1part[2][tid] + l1part[3][tid];
    const float A = alpart[0][tid] + alpart[1][tid] + alpart[2][tid] + alpart[3][tid];
    float c = lblLds[tid] ? (L - 2.f * A) / fmaxf(L, 1e-12f) : 0.f;
#pragma unroll
    for (int off = 1; off < 64; off <<= 1) c += __shfl_xor(c, off);
    if (tid == 0) atomicAdd(out, c);
  }
}

extern "C" void kernel_launch(void* const* d_in, const int* in_sizes, int n_in,
                              void* d_out, int out_size, void* d_ws, size_t ws_size,
                              hipStream_t stream) {
  const float* feats = (const float*)d_in[0];
  const float* centers = (const float*)d_in[1];
  const int* labels = (const int*)d_in[2];
  const int* labelled = (const int*)d_in[3];
  float* out = (float*)d_out;
  short* cnb2 = (short*)d_ws;  // [24][256][32] bf16, quad-swizzle baked in

  prep_centers_k<<<CPAD, 256, 0, stream>>>(centers, cnb2, out);
  cos_loss_k<<<NROWS / ROWSB, 256, 0, stream>>>(feats, cnb2, labels, labelled, out);
}